// Round 2
// baseline (228.717 us; speedup 1.0000x reference)
//
#include <hip/hip_runtime.h>
#include <hip/hip_bf16.h>

// ---------------------------------------------------------------------------
// MMD loss:  mmd = Sxx_offdiag/(n(n-1)) + Syy_offdiag/(m(m-1)) - 2*Sxy/(n*m)
// k(a,b) = exp(-|a-b|^2/128).  N = M = 8192, D = 64.
//
// exp2 domain: k = exp2( (a.b)*C2L - sx2 - sy2 ), where
//   sx2 = |a|^2 * log2e/128 (precomputed), C2L = log2e/64.
// bf16 MFMA 16x16x32, K=64 via 2 chained MFMAs.  Clean waves (strictly above
// diagonal, or XY) run a branch-free software-pipelined loop; only the 128
// diagonal-straddling blocks take the predicated path.  Per-block partial is
// scaled and atomicAdd'd (double); last block (ticket) writes clamped output.
// ---------------------------------------------------------------------------

using short8 = __attribute__((ext_vector_type(8))) short;  // 8 bf16 (4 VGPRs)
using f32x4  = __attribute__((ext_vector_type(4))) float;  // 4 fp32

#define NROWS 8192
#define DDIM  64
#define LOG2E 1.4426950408889634f
#define TOTAL_BLOCKS 6144

// ---------------------------------------------------------------------------
// Prep: normalize X, cast X/Y to bf16, squared norms pre-scaled by log2e/128.
// ---------------------------------------------------------------------------
__global__ __launch_bounds__(256) void mmd_prep(
    const float* __restrict__ z_seq, const float* __restrict__ pmean,
    const float* __restrict__ pstd, const float* __restrict__ z_prior,
    __hip_bfloat16* __restrict__ Xb, __hip_bfloat16* __restrict__ Yb,
    float* __restrict__ sxx, float* __restrict__ syy)
{
    const int tid  = threadIdx.x;
    const int lane = tid & 63;
    const int wid  = tid >> 6;
    const int row  = blockIdx.x * 4 + wid;   // 0..16383 (X rows then Y rows)

    float v;
    __hip_bfloat16* dst;
    float* sdst;
    int r;
    if (row < NROWS) {
        r = row;
        v = (z_seq[(size_t)r * DDIM + lane] - pmean[lane]) / pstd[lane];
        dst = Xb; sdst = sxx;
    } else {
        r = row - NROWS;
        v = z_prior[(size_t)r * DDIM + lane];
        dst = Yb; sdst = syy;
    }
    __hip_bfloat16 hb = __float2bfloat16(v);
    dst[(size_t)r * DDIM + lane] = hb;

    float vb = __bfloat162float(hb);
    float sq = vb * vb;
#pragma unroll
    for (int off = 32; off; off >>= 1) sq += __shfl_xor(sq, off, 64);
    if (lane == 0) sdst[r] = sq * (LOG2E / 128.0f);
}

// ---------------------------------------------------------------------------
// Clean wave: 64(i) x 128(j) tile, all pairs valid (j>i guaranteed by caller
// for symmetric modes).  Branch-free, software-pipelined B prefetch.
// ---------------------------------------------------------------------------
__device__ __forceinline__ float wave_clean(
    const __hip_bfloat16* __restrict__ A, const __hip_bfloat16* __restrict__ Bp,
    const float* __restrict__ sa2, const float* __restrict__ sb2,
    int i0, int j0, int lane)
{
    const int quad = lane >> 4;
    const int l15  = lane & 15;
    constexpr float C2L = LOG2E / 64.0f;

    short8 af[4][2];
    float  nsx[4][4];
    const __hip_bfloat16* Ap = A + (size_t)(i0 + l15) * DDIM + quad * 8;
#pragma unroll
    for (int mt = 0; mt < 4; ++mt) {
        af[mt][0] = *reinterpret_cast<const short8*>(Ap + mt * 16 * DDIM);
        af[mt][1] = *reinterpret_cast<const short8*>(Ap + mt * 16 * DDIM + 32);
        const float* sp = sa2 + i0 + mt * 16 + quad * 4;
#pragma unroll
        for (int r = 0; r < 4; ++r) nsx[mt][r] = -sp[r];
    }

    const __hip_bfloat16* Bw = Bp + (size_t)(j0 + l15) * DDIM + quad * 8;
    const float* syp = sb2 + j0 + l15;

    short8 b0c = *reinterpret_cast<const short8*>(Bw);
    short8 b1c = *reinterpret_cast<const short8*>(Bw + 32);
    float  syc = syp[0];

    float ls0 = 0.f, ls1 = 0.f, ls2 = 0.f, ls3 = 0.f;

#pragma unroll
    for (int nt = 0; nt < 8; ++nt) {
        short8 b0n, b1n; float syn;
        if (nt < 7) {
            b0n = *reinterpret_cast<const short8*>(Bw + (nt + 1) * 16 * DDIM);
            b1n = *reinterpret_cast<const short8*>(Bw + (nt + 1) * 16 * DDIM + 32);
            syn = syp[(nt + 1) * 16];
        }
        f32x4 acc[4];
#pragma unroll
        for (int mt = 0; mt < 4; ++mt) {
            f32x4 a0 = {0.f, 0.f, 0.f, 0.f};
            a0      = __builtin_amdgcn_mfma_f32_16x16x32_bf16(af[mt][0], b0c, a0, 0, 0, 0);
            acc[mt] = __builtin_amdgcn_mfma_f32_16x16x32_bf16(af[mt][1], b1c, a0, 0, 0, 0);
        }
#pragma unroll
        for (int mt = 0; mt < 4; ++mt) {
            ls0 += __builtin_amdgcn_exp2f(fmaf(acc[mt][0], C2L, nsx[mt][0] - syc));
            ls1 += __builtin_amdgcn_exp2f(fmaf(acc[mt][1], C2L, nsx[mt][1] - syc));
            ls2 += __builtin_amdgcn_exp2f(fmaf(acc[mt][2], C2L, nsx[mt][2] - syc));
            ls3 += __builtin_amdgcn_exp2f(fmaf(acc[mt][3], C2L, nsx[mt][3] - syc));
        }
        if (nt < 7) { b0c = b0n; b1c = b1n; syc = syn; }
    }
    return (ls0 + ls1) + (ls2 + ls3);
}

// ---------------------------------------------------------------------------
// Diagonal-straddling wave (only in the 128 straddle blocks): tile-level
// skip below diagonal, per-element j>i mask on diagonal tiles.
// ---------------------------------------------------------------------------
__device__ __forceinline__ float wave_diag(
    const __hip_bfloat16* __restrict__ A, const __hip_bfloat16* __restrict__ Bp,
    const float* __restrict__ sa2, const float* __restrict__ sb2,
    int i0, int j0, int lane)
{
    const int quad = lane >> 4;
    const int l15  = lane & 15;
    constexpr float C2L = LOG2E / 64.0f;

    short8 af[4][2];
    float  nsx[4][4];
    const __hip_bfloat16* Ap = A + (size_t)(i0 + l15) * DDIM + quad * 8;
#pragma unroll
    for (int mt = 0; mt < 4; ++mt) {
        af[mt][0] = *reinterpret_cast<const short8*>(Ap + mt * 16 * DDIM);
        af[mt][1] = *reinterpret_cast<const short8*>(Ap + mt * 16 * DDIM + 32);
        const float* sp = sa2 + i0 + mt * 16 + quad * 4;
#pragma unroll
        for (int r = 0; r < 4; ++r) nsx[mt][r] = -sp[r];
    }

    const __hip_bfloat16* Bw = Bp + (size_t)(j0 + l15) * DDIM + quad * 8;
    const float* syp = sb2 + j0 + l15;

    float lsum = 0.f;
#pragma unroll
    for (int nt = 0; nt < 8; ++nt) {
        const int jt = j0 + nt * 16;
        if (jt < i0) continue;                 // whole strip below diagonal
        short8 b0 = *reinterpret_cast<const short8*>(Bw + nt * 16 * DDIM);
        short8 b1 = *reinterpret_cast<const short8*>(Bw + nt * 16 * DDIM + 32);
        const float syv = syp[nt * 16];
#pragma unroll
        for (int mt = 0; mt < 4; ++mt) {
            const int it = i0 + mt * 16;
            if (jt < it) continue;             // tile strictly below diagonal
            f32x4 a0 = {0.f, 0.f, 0.f, 0.f};
            a0 = __builtin_amdgcn_mfma_f32_16x16x32_bf16(af[mt][0], b0, a0, 0, 0, 0);
            f32x4 acc = __builtin_amdgcn_mfma_f32_16x16x32_bf16(af[mt][1], b1, a0, 0, 0, 0);
            if (jt == it) {
#pragma unroll
                for (int r = 0; r < 4; ++r) {
                    float v = __builtin_amdgcn_exp2f(fmaf(acc[r], C2L, nsx[mt][r] - syv));
                    lsum += (l15 > quad * 4 + r) ? v : 0.f;   // strictly j>i
                }
            } else {
#pragma unroll
                for (int r = 0; r < 4; ++r)
                    lsum += __builtin_amdgcn_exp2f(fmaf(acc[r], C2L, nsx[mt][r] - syv));
            }
        }
    }
    return lsum;
}

// ---------------------------------------------------------------------------
// Main: grid (32 bj, 64 bi, 3 modes).  Block tile 128(i) x 256(j), 4 waves.
// Last block (ticket) writes the clamped scalar output.
// ---------------------------------------------------------------------------
__global__ __launch_bounds__(256) void mmd_main(
    const __hip_bfloat16* __restrict__ Xb, const __hip_bfloat16* __restrict__ Yb,
    const float* __restrict__ sxx, const float* __restrict__ syy,
    double* __restrict__ accum,   // [0]=sum (double), [1]=ticket counter (uint)
    float* __restrict__ out)
{
    const int mode = blockIdx.z;
    const int bj = blockIdx.x;
    const int bi = blockIdx.y;

    const __hip_bfloat16* A;
    const __hip_bfloat16* Bp;
    const float* sa;
    const float* sb;
    if (mode == 0)      { A = Xb; Bp = Xb; sa = sxx; sb = sxx; }
    else if (mode == 1) { A = Yb; Bp = Yb; sa = syy; sb = syy; }
    else                { A = Xb; Bp = Yb; sa = sxx; sb = syy; }
    const bool sym = (mode < 2);

    const int tid  = threadIdx.x;
    const int lane = tid & 63;
    const int wid  = tid >> 6;

    const int iBlock = bi * 128;
    const int jBlock = bj * 256;

    float wsum = 0.f;
    if (!(sym && (jBlock + 256 <= iBlock))) {      // skip dead blocks' work
        const int i0 = iBlock + (wid >> 1) * 64;
        const int j0 = jBlock + (wid & 1) * 128;
        if (!sym || j0 >= i0 + 64)
            wsum = wave_clean(A, Bp, sa, sb, i0, j0, lane);
        else
            wsum = wave_diag(A, Bp, sa, sb, i0, j0, lane);
    }

#pragma unroll
    for (int off = 32; off; off >>= 1) wsum += __shfl_xor(wsum, off, 64);

    __shared__ float ws4[4];
    if (lane == 0) ws4[wid] = wsum;
    __syncthreads();
    if (tid == 0) {
        // symmetric modes: computed strictly-upper triangle; x2 folded in coef
        const double coef = sym ? (2.0 / (8192.0 * 8191.0))
                                : (-2.0 / (8192.0 * 8192.0));
        const double c = (double)(ws4[0] + ws4[1] + ws4[2] + ws4[3]) * coef;
        atomicAdd(accum, c);
        __threadfence();
        unsigned* cnt = (unsigned*)(accum + 1);
        unsigned ticket = atomicAdd(cnt, 1u);
        if (ticket == TOTAL_BLOCKS - 1) {
            double v = atomicAdd(accum, 0.0);   // device-scope read
            out[0] = (float)(v > 0.0 ? v : 0.0);
        }
    }
}

// ---------------------------------------------------------------------------
extern "C" void kernel_launch(void* const* d_in, const int* in_sizes, int n_in,
                              void* d_out, int out_size, void* d_ws, size_t ws_size,
                              hipStream_t stream) {
    const float* z_seq   = (const float*)d_in[0];   // [16,512,64]
    const float* pmean   = (const float*)d_in[1];   // [64]
    const float* pstd    = (const float*)d_in[2];   // [64]
    const float* z_prior = (const float*)d_in[3];   // [8192,64]
    float* out = (float*)d_out;

    char* ws = (char*)d_ws;
    __hip_bfloat16* Xb = (__hip_bfloat16*)(ws);                    // 1 MB
    __hip_bfloat16* Yb = (__hip_bfloat16*)(ws + (1u << 20));       // 1 MB
    float* sxx = (float*)(ws + (2u << 20));                        // 32 KB
    float* syy = (float*)(ws + (2u << 20) + 32768);                // 32 KB
    double* accum = (double*)(ws + (2u << 20) + 65536);            // 16 B

    hipMemsetAsync(accum, 0, 16, stream);          // zero sum + ticket
    mmd_prep<<<dim3(4096), dim3(256), 0, stream>>>(
        z_seq, pmean, pstd, z_prior, Xb, Yb, sxx, syy);
    mmd_main<<<dim3(32, 64, 3), dim3(256), 0, stream>>>(
        Xb, Yb, sxx, syy, accum, out);
}